// Round 9
// baseline (174.015 us; speedup 1.0000x reference)
//
#include <hip/hip_runtime.h>

// Geometry (compile-time, from reference)
constexpr int Bn = 8, Dn = 64, Hn = 128, Wn = 64;
constexpr int sH = 64;
constexpr int sD = 8192;      // Hn*Wn
constexpr int sC = 524288;    // Dn*sD
constexpr int sB = 2097152;   // 4*sC

// Grid spacings
constexpr double DXd = 2.5 / 63.0;
constexpr double DYd = 1.0 / 127.0;
constexpr double DZd = 0.8 / 63.0;
constexpr float I2DX = (float)(0.5 / DXd);
constexpr float I2DY = (float)(0.5 / DYd);
constexpr float I2DZ = (float)(0.5 / DZd);
constexpr float IDX2 = (float)(1.0 / (DXd * DXd));
constexpr float IDY2 = (float)(1.0 / (DYd * DYd));
constexpr float IDZ2 = (float)(1.0 / (DZd * DZd));
constexpr float INV_RE = 1.0e-6f;

// weights / counts
constexpr float CF  = (float)(1.0  / (8.0 * 4.0 * 64.0 * 128.0 * 64.0));
constexpr float CCT = (float)(10.0 / 8.0);
constexpr float CCM = (float)(1.0  / (8.0 * 62.0 * 126.0 * 62.0));
constexpr float CN  = (float)(10.0 / (8.0 * 64.0 * 128.0 * 64.0));
constexpr float CI  = (float)(5.0  / (8.0 * 64.0 * 128.0));
constexpr float CO  = (float)(1.0  / (8.0 * 64.0 * 128.0));

__device__ __forceinline__ float4 ld4(const float* p, int off) {
    return *reinterpret_cast<const float4*>(p + off);
}

// async global->LDS DMA, 16B per lane; LDS dest = uniform base + lane*16
__device__ __forceinline__ void dma16(const float* g, float* l) {
    __builtin_amdgcn_global_load_lds(
        (const __attribute__((address_space(1))) void*)g,
        (__attribute__((address_space(3))) void*)l,
        16, 0, 0);
}

// Block: 128 threads (2 waves). Tile: 8 h-rows x 64 W, marches 8 z-planes.
// LDS: 4-slot ring of field planes, [slot][ch][row: 0=hm,1..8=core,9=hp][w].
// DMA stages plane d+2 while computing plane d; counted vmcnt keeps the
// pipeline full (never drained to 0 mid-loop).
__global__ __launch_bounds__(128) void fno3d_main(
    const float* __restrict__ field,
    const float* __restrict__ gt_field,
    const float* __restrict__ sdf,
    float* __restrict__ partials)
{
    __shared__ float lds[4][4][10][64];   // 40960 B -> 4 blocks/CU

    const int tid = threadIdx.x;          // 0..127
    const int x   = tid & 15;             // w quad
    const int ty  = (tid >> 4) & 7;       // row in tile
    const int wv  = tid >> 6;             // wave id
    const int lx  = tid & 63;             // lane

    const int blk = blockIdx.x;           // 0..1023
    const int b   = blk >> 7;
    const int rem = blk & 127;
    const int d0  = (rem >> 4) << 3;      // 8 z-segments of 8 planes
    const int h0  = (rem & 15) << 3;      // 16 h-tiles of 8 rows
    const int h   = h0 + ty;
    const int w0  = x << 2;

    const float* Fb = field    + b * sB;
    const float* Gb = gt_field + b * sB;
    const float* Sb = sdf      + b * sC;

    const int hmg = (h0 > 0) ? h0 - 1 : 0;
    const int hpg = (h0 + 8 < Hn) ? h0 + 8 : Hn - 1;
    const int rowc = h * sH + w0;
    const bool hIn = (h >= 1) && (h <= Hn - 2);

    // halo lane mapping: tid -> (which row, channel, 16B unit)
    const int hch    = (tid >> 4) & 3;
    const int hwhich = tid >> 6;          // 0 => hm, 1 => hp
    const int hrow   = hwhich ? hpg : hmg;

    // stage 8 core rows of one field plane: 8 KB = 8 chunks, 4 per wave
    auto stage_core = [&](int p, int s) {
        #pragma unroll
        for (int c = 0; c < 4; ++c) {
            const int ch   = (wv << 1) | (c >> 1);
            const int half = c & 1;
            const float* g = Fb + ch * sC + p * sD
                           + (h0 + half * 4 + (lx >> 4)) * sH + ((lx & 15) << 2);
            dma16(g, &lds[s][ch][1 + half * 4][0]);
        }
    };
    auto load_halo = [&](int p) {
        return ld4(Fb, hch * sC + p * sD + hrow * sH + w0);
    };

    // ---- prologue: field planes d0-1, d0, d0+1; gt/sdf(d0); halos d0,d0+1 ----
    stage_core((d0 > 0) ? d0 - 1 : 0, 3);
    stage_core(d0, 0);
    stage_core(d0 + 1, 1);

    float4 gtb[2][4], sdb[2], hb[2];
    gtb[0][0] = ld4(Gb, d0 * sD + rowc);
    gtb[0][1] = ld4(Gb, sC + d0 * sD + rowc);
    gtb[0][2] = ld4(Gb, 2 * sC + d0 * sD + rowc);
    gtb[0][3] = ld4(Gb, 3 * sC + d0 * sD + rowc);
    sdb[0]    = ld4(Sb, d0 * sD + rowc);
    hb[0] = load_halo(d0);
    hb[1] = load_halo(d0 + 1);
    *(float4*)&lds[0][hch][hwhich * 9][w0] = hb[0];   // halo(d0) -> slot 0

    float acc = 0.f;

    #pragma unroll
    for (int k = 0; k < 8; ++k) {
        const int d  = d0 + k;
        const int sc = k & 3, sp = (k + 3) & 3, sn = (k + 1) & 3;

        // ---- issue phase: everything for later iterations ----
        if (k < 7) {
            const int d1 = (d + 1 < Dn) ? d + 1 : Dn - 1;
            gtb[(k + 1) & 1][0] = ld4(Gb, d1 * sD + rowc);
            gtb[(k + 1) & 1][1] = ld4(Gb, sC + d1 * sD + rowc);
            gtb[(k + 1) & 1][2] = ld4(Gb, 2 * sC + d1 * sD + rowc);
            gtb[(k + 1) & 1][3] = ld4(Gb, 3 * sC + d1 * sD + rowc);
            sdb[(k + 1) & 1]    = ld4(Sb, d1 * sD + rowc);
        }
        if (k < 6) {
            const int d2 = (d + 2 < Dn) ? d + 2 : Dn - 1;
            hb[k & 1] = load_halo(d2);
        }
        if (k < 7) {
            const int d2 = (d + 2 < Dn) ? d + 2 : Dn - 1;
            stage_core(d2, (k + 2) & 3);
        }
        if (k <= 6) {  // halo(d+1) from regs loaded last step
            *(float4*)&lds[sn][hch][hwhich * 9][w0] = hb[(k + 1) & 1];
        }

        // counted wait: only this step's issues may remain in flight
        if (k < 6)       asm volatile("s_waitcnt vmcnt(10) lgkmcnt(0)" ::: "memory");
        else if (k == 6) asm volatile("s_waitcnt vmcnt(9) lgkmcnt(0)" ::: "memory");
        else             asm volatile("s_waitcnt vmcnt(0) lgkmcnt(0)" ::: "memory");
        __builtin_amdgcn_s_barrier();

        // ---- compute plane d entirely from LDS + prefetched regs ----
        const float4 cU  = *(const float4*)&lds[sc][0][1 + ty][w0];
        const float4 cV  = *(const float4*)&lds[sc][1][1 + ty][w0];
        const float4 cW  = *(const float4*)&lds[sc][2][1 + ty][w0];
        const float4 cP  = *(const float4*)&lds[sc][3][1 + ty][w0];
        const float4 zpU = *(const float4*)&lds[sp][0][1 + ty][w0];
        const float4 zpV = *(const float4*)&lds[sp][1][1 + ty][w0];
        const float4 zpW = *(const float4*)&lds[sp][2][1 + ty][w0];
        const float4 zpP = *(const float4*)&lds[sp][3][1 + ty][w0];
        const float4 znU = *(const float4*)&lds[sn][0][1 + ty][w0];
        const float4 znV = *(const float4*)&lds[sn][1][1 + ty][w0];
        const float4 znW = *(const float4*)&lds[sn][2][1 + ty][w0];
        const float4 znP = *(const float4*)&lds[sn][3][1 + ty][w0];
        const float4 yUm = *(const float4*)&lds[sc][0][ty][w0];
        const float4 yUp = *(const float4*)&lds[sc][0][2 + ty][w0];
        const float4 yVm = *(const float4*)&lds[sc][1][ty][w0];
        const float4 yVp = *(const float4*)&lds[sc][1][2 + ty][w0];
        const float4 yWm = *(const float4*)&lds[sc][2][ty][w0];
        const float4 yWp = *(const float4*)&lds[sc][2][2 + ty][w0];
        const float4 yPm = *(const float4*)&lds[sc][3][ty][w0];
        const float4 yPp = *(const float4*)&lds[sc][3][2 + ty][w0];

        const float uLs = __shfl_up(cU.w, 1), uRs = __shfl_down(cU.x, 1);
        const float vLs = __shfl_up(cV.w, 1), vRs = __shfl_down(cV.x, 1);
        const float wLs = __shfl_up(cW.w, 1), wRs = __shfl_down(cW.x, 1);
        const float pLs = __shfl_up(cP.w, 1), pRs = __shfl_down(cP.x, 1);

        const float* au = (const float*)&cU;  const float* av = (const float*)&cV;
        const float* aw = (const float*)&cW;  const float* ap = (const float*)&cP;
        const float* apu = (const float*)&zpU; const float* apv = (const float*)&zpV;
        const float* apw = (const float*)&zpW; const float* app = (const float*)&zpP;
        const float* anu = (const float*)&znU; const float* anv = (const float*)&znV;
        const float* anw = (const float*)&znW; const float* anp = (const float*)&znP;
        const float* ayum = (const float*)&yUm; const float* ayup = (const float*)&yUp;
        const float* ayvm = (const float*)&yVm; const float* ayvp = (const float*)&yVp;
        const float* aywm = (const float*)&yWm; const float* aywp = (const float*)&yWp;
        const float* aypm = (const float*)&yPm; const float* aypp = (const float*)&yPp;
        const float* agu = (const float*)&gtb[k & 1][0];
        const float* agv = (const float*)&gtb[k & 1][1];
        const float* agw = (const float*)&gtb[k & 1][2];
        const float* agp = (const float*)&gtb[k & 1][3];
        const float* as_ = (const float*)&sdb[k & 1];

        const bool dIn = (d >= 1) && (d <= Dn - 2);

        #pragma unroll
        for (int e = 0; e < 4; ++e) {
            const int w = w0 + e;
            const float u = au[e], v = av[e], wq = aw[e], pq = ap[e];

            { // field MSE
                const float e0 = u  - agu[e];
                const float e1 = v  - agv[e];
                const float e2 = wq - agw[e];
                const float e3 = pq - agp[e];
                acc += CF * (e0 * e0 + e1 * e1 + e2 * e2 + e3 * e3);
            }

            const float s = as_[e];
            acc += ((s <= 0.f) ? CN : 0.f) * (u * u + v * v + wq * wq);

            { // inlet (w==0)
                const float du = u - 1.0f;
                acc += ((w == 0) ? CI : 0.f) * (du * du + v * v + wq * wq);
            }

            const float uxm = (e == 0) ? uLs : au[e - 1];
            const float uxp = (e == 3) ? uRs : au[e + 1];
            const float vxm = (e == 0) ? vLs : av[e - 1];
            const float vxp = (e == 3) ? vRs : av[e + 1];
            const float wxm = (e == 0) ? wLs : aw[e - 1];
            const float wxp = (e == 3) ? wRs : aw[e + 1];
            const float pxm = (e == 0) ? pLs : ap[e - 1];
            const float pxp = (e == 3) ? pRs : ap[e + 1];

            const float du_dx = (uxp - uxm) * I2DX;
            const float du_dy = (ayup[e] - ayum[e]) * I2DY;
            const float du_dz = (anu[e] - apu[e]) * I2DZ;
            const float dv_dx = (vxp - vxm) * I2DX;
            const float dv_dy = (ayvp[e] - ayvm[e]) * I2DY;
            const float dv_dz = (anv[e] - apv[e]) * I2DZ;
            const float dw_dx = (wxp - wxm) * I2DX;
            const float dw_dy = (aywp[e] - aywm[e]) * I2DY;
            const float dw_dz = (anw[e] - apw[e]) * I2DZ;
            const float dp_dx = (pxp - pxm) * I2DX;
            const float dp_dy = (aypp[e] - aypm[e]) * I2DY;
            const float dp_dz = (anp[e] - app[e]) * I2DZ;

            const float div = du_dx + dv_dy + dw_dz;

            const float lap_u = (uxp - 2.f * u  + uxm) * IDX2 + (ayup[e] - 2.f * u  + ayum[e]) * IDY2 + (anu[e] - 2.f * u  + apu[e]) * IDZ2;
            const float lap_v = (vxp - 2.f * v  + vxm) * IDX2 + (ayvp[e] - 2.f * v  + ayvm[e]) * IDY2 + (anv[e] - 2.f * v  + apv[e]) * IDZ2;
            const float lap_w = (wxp - 2.f * wq + wxm) * IDX2 + (aywp[e] - 2.f * wq + aywm[e]) * IDY2 + (anw[e] - 2.f * wq + apw[e]) * IDZ2;

            const float rx = u * du_dx + v * du_dy + wq * du_dz + dp_dx - INV_RE * lap_u;
            const float ry = u * dv_dx + v * dv_dy + wq * dv_dz + dp_dy - INV_RE * lap_v;
            const float rz = u * dw_dx + v * dw_dy + wq * dw_dz + dp_dz - INV_RE * lap_w;

            const bool wIn = (w >= 1) && (w <= Wn - 2);
            const float m = (s > 0.f && wIn && hIn && dIn) ? CCM : 0.f;
            acc += m * (div * div + rx * rx + ry * ry + rz * rz);
        }

        if (x == 15) { // outlet
            const float a0 = au[3] - au[2];
            const float a1 = av[3] - av[2];
            const float a2 = aw[3] - aw[2];
            acc += CO * (a0 * a0 + a1 * a1 + a2 * a2);
        }

        __builtin_amdgcn_s_barrier();   // protect ring slot before next stage
    }

    // reduce 2 waves -> one partial per block
    for (int off = 32; off > 0; off >>= 1)
        acc += __shfl_down(acc, off);
    __syncthreads();
    if ((tid & 63) == 0) ((float*)lds)[wv] = acc;
    __syncthreads();
    if (tid == 0) partials[blk] = ((float*)lds)[0] + ((float*)lds)[1];
}

// Final reduce: 1024 partials + ct term -> out[0]
__global__ __launch_bounds__(256) void fno3d_reduce(
    const float* __restrict__ partials,
    const float* __restrict__ ct,
    const float* __restrict__ gt_ct,
    float* __restrict__ out)
{
    const int t = threadIdx.x;
    float s = partials[t] + partials[t + 256] + partials[t + 512] + partials[t + 768];
    for (int off = 32; off > 0; off >>= 1)
        s += __shfl_down(s, off);

    __shared__ float wsum[4];
    if ((t & 63) == 0) wsum[t >> 6] = s;
    __syncthreads();
    if (t == 0) {
        float tot = wsum[0] + wsum[1] + wsum[2] + wsum[3];
        float ctl = 0.f;
        for (int i = 0; i < Bn; ++i) {
            const float dc = ct[i] - gt_ct[i];
            ctl += dc * dc;
        }
        out[0] = tot + CCT * ctl;
    }
}

extern "C" void kernel_launch(void* const* d_in, const int* in_sizes, int n_in,
                              void* d_out, int out_size, void* d_ws, size_t ws_size,
                              hipStream_t stream) {
    const float* field    = (const float*)d_in[0];
    const float* ct       = (const float*)d_in[1];
    const float* gt_field = (const float*)d_in[2];
    const float* gt_ct    = (const float*)d_in[3];
    const float* sdf      = (const float*)d_in[4];
    float* out      = (float*)d_out;
    float* partials = (float*)d_ws;   // 1024 floats scratch

    hipLaunchKernelGGL(fno3d_main, dim3(1024), dim3(128), 0, stream,
                       field, gt_field, sdf, partials);
    hipLaunchKernelGGL(fno3d_reduce, dim3(1), dim3(256), 0, stream,
                       partials, ct, gt_ct, out);
}